// Round 13
// baseline (280.772 us; speedup 1.0000x reference)
//
#include <hip/hip_runtime.h>
#include <hip/hip_bf16.h>

#define B_ 8
#define S_ 2048
#define F_ 1024
#define D_ 1024
#define TRI_ 136            // 16*17/2 causal tiles per batch (128x128)
#define TELEM_ 16384        // elems per 128x128 tile

typedef unsigned short u16;
typedef float f32x4 __attribute__((ext_vector_type(4)));
typedef __bf16 bf16x8 __attribute__((ext_vector_type(8)));
typedef unsigned short u16x8 __attribute__((ext_vector_type(8)));

__device__ __forceinline__ u16 f2bf(float f) {
  union { float f; unsigned u; } v; v.f = f;
  unsigned r = v.u + 0x7fff + ((v.u >> 16) & 1);
  return (u16)(r >> 16);
}
__device__ __forceinline__ float bf2f(u16 b) {
  union { unsigned u; float f; } v; v.u = ((unsigned)b) << 16;
  return v.f;
}

__device__ __forceinline__ void stage16(const u16* g, u16* l) {
  __builtin_amdgcn_global_load_lds(
      (const __attribute__((address_space(1))) void*)g,
      (__attribute__((address_space(3))) void*)l, 16, 0, 0);
}

// bijective XCD-chunk swizzle: n must be divisible by 8
__device__ __forceinline__ int xcd_swz(int f, int n) {
  int per = n >> 3;
  return (f & 7) * per + (f >> 3);
}

// ---------------- prep: fused cast_x + transW ----------------

__global__ __launch_bounds__(256) void prep(const float* __restrict__ x,
                                            const float* __restrict__ Wq,
                                            const float* __restrict__ Wk,
                                            const float* __restrict__ Wv,
                                            u16* __restrict__ xb,
                                            u16* __restrict__ Wt) {
  __shared__ float tile[32][33];
  if (blockIdx.x < 2048) {
    int n4 = (B_ * S_ * F_) / 4;
    for (int i = blockIdx.x * 256 + threadIdx.x; i < n4; i += 2048 * 256) {
      float4 v = ((const float4*)x)[i];
      ushort4 o;
      o.x = f2bf(v.x); o.y = f2bf(v.y); o.z = f2bf(v.z); o.w = f2bf(v.w);
      ((ushort4*)xb)[i] = o;
    }
  } else {
    int f = blockIdx.x - 2048;     // 0..3071
    int z = f >> 10;
    int f2 = f & 1023;
    int f0 = (f2 >> 5) * 32, d0 = (f2 & 31) * 32;
    const float* W = (z == 0) ? Wq : ((z == 1) ? Wk : Wv);
    int tx = threadIdx.x & 31, ty = threadIdx.x >> 5;
    for (int i = 0; i < 4; i++)
      tile[ty + i * 8][tx] = W[(size_t)(f0 + ty + i * 8) * D_ + d0 + tx];
    __syncthreads();
    u16* o = Wt + (size_t)z * D_ * F_;
    for (int i = 0; i < 4; i++)
      o[(size_t)(d0 + ty + i * 8) * F_ + f0 + tx] = f2bf(tile[tx][ty + i * 8]);
  }
}

// er = tile-packed bf16 r-softmax with mask sentinel; also zeroes rowsum
__global__ __launch_bounds__(256) void er_pass(const float* __restrict__ r,
                                               const float* __restrict__ pm,
                                               u16* __restrict__ er,
                                               float* __restrict__ rowsum) {
  int row = blockIdx.x;            // b*S + s
  int b = row >> 11, s = row & 2047;
  if (threadIdx.x == 0) rowsum[row] = 0.f;
  const float4* rp = (const float4*)(r + (size_t)row * S_);
  const float4* pp = (const float4*)(pm + (size_t)b * S_);
  int nk = (s >> 2) + 1;           // quads containing kept cols
  int nw = ((s >> 7) + 1) << 5;    // write quads (128-rounded extent / 4)
  float4 ev[8];
  float acc = 0.f;
  #pragma unroll
  for (int it = 0; it < 8; it++) {
    int i = threadIdx.x + it * 256;
    if (i < nk) {
      float4 rv = rp[i], pv = pp[i];
      int t0 = i << 2;
      float4 e;
      #pragma unroll
      for (int j = 0; j < 4; j++) {
        bool keep = (t0 + j <= s) && ((&pv.x)[j] != 0.f);
        (&e.x)[j] = keep ? __expf((&rv.x)[j] - 16.f) : 0.f;
        acc += (&e.x)[j];
      }
      ev[it] = e;
    }
  }
  for (int off = 1; off < 64; off <<= 1) acc += __shfl_xor(acc, off);
  __shared__ float wsum[4];
  int lane = threadIdx.x & 63, w = threadIdx.x >> 6;
  if (lane == 0) wsum[w] = acc;
  __syncthreads();
  float invr = 1.f / (wsum[0] + wsum[1] + wsum[2] + wsum[3]);
  int c = s >> 7, rin = s & 127;
  u16* tb = er + (size_t)(b * TRI_ + c * (c + 1) / 2) * TELEM_ + rin * 128;
  #pragma unroll
  for (int it = 0; it < 8; it++) {
    int i = threadIdx.x + it * 256;
    if (i < nw) {
      int t0 = i << 2;
      float4 pv = pp[i];
      ushort4 o;
      #pragma unroll
      for (int j = 0; j < 4; j++) {
        bool keep = (t0 + j <= s) && ((&pv.x)[j] != 0.f);
        float val = keep ? (&ev[it].x)[j] * invr : -1e9f;
        (&o.x)[j] = f2bf(val);
      }
      *(ushort4*)(tb + (size_t)(t0 >> 7) * TELEM_ + (t0 & 127)) = o;
    }
  }
}

// fallback row-sum only (when ws too small for er)
__global__ __launch_bounds__(256) void r_rowsum(const float* __restrict__ r,
                                                const float* __restrict__ pm,
                                                float* __restrict__ rs) {
  int row = blockIdx.x;
  int b = row >> 11, s = row & 2047;
  const float4* rp = (const float4*)(r + (size_t)row * S_);
  const float4* pp = (const float4*)(pm + (size_t)b * S_);
  int nv = (s >> 2) + 1;
  float acc = 0.f;
  for (int i = threadIdx.x; i < nv; i += 256) {
    float4 rv = rp[i];
    float4 pv = pp[i];
    int t0 = i << 2;
    #pragma unroll
    for (int j = 0; j < 4; j++) {
      int t = t0 + j;
      if (t <= s && (&pv.x)[j] != 0.f) acc += __expf((&rv.x)[j] - 16.f);
    }
  }
  for (int off = 1; off < 64; off <<= 1) acc += __shfl_xor(acc, off);
  __shared__ float wsum[4];
  int lane = threadIdx.x & 63, w = threadIdx.x >> 6;
  if (lane == 0) wsum[w] = acc;
  __syncthreads();
  if (threadIdx.x == 0) rs[row] = wsum[0] + wsum[1] + wsum[2] + wsum[3];
}

// ---------------- shared GEMM helpers ----------------

__device__ __forceinline__ bf16x8 readfrag(const u16* lds, int row, int ks, int hi) {
  int c = ((ks << 6) + (hi << 4)) ^ ((row & 7) << 4);
  return *(const bf16x8*)((const char*)lds + row * 128 + c);
}

#define SYNC_POINT()                                                             \
  __builtin_amdgcn_sched_barrier(0);                                             \
  __builtin_amdgcn_s_barrier();                                                  \
  __builtin_amdgcn_sched_barrier(0);

#define LGK0()                                                                   \
  asm volatile("s_waitcnt lgkmcnt(0)" ::: "memory");                             \
  __builtin_amdgcn_sched_barrier(0);

// =============== 256x256 / BK=64 / 8-wave engine, m201 phase structure =======
// Per K-tile: 4 phases of {ds_read own frags | stage 1 half-tile -> barrier ->
// lgkmcnt(0) -> 16 MFMA -> barrier}. Counted vmcnt chain from r8 (proven):
// Ph2 vmcnt(4) covers beta(t)+alpha(t+1); Ph4 vmcnt(4/2) covers B(t+1).

__device__ __forceinline__ void stageA(const u16* __restrict__ src, int ld, int h,
                                       u16* ldsA, int w, int l) {
  int base = ((w >> 2) * 128) + h * 64 + ((w & 3) * 16);
  int r = l >> 3, ch = (l & 7) ^ (l >> 3);
  #pragma unroll
  for (int i = 0; i < 2; i++) {
    int row = base + i * 8;
    stage16(src + (size_t)(row + r) * ld + ch * 8, ldsA + row * 64);
  }
}
__device__ __forceinline__ void stageB(const u16* __restrict__ src, int ld, int h,
                                       u16* ldsB, int w, int l) {
  int base = h * 128 + w * 16;
  int r = l >> 3, ch = (l & 7) ^ (l >> 3);
  #pragma unroll
  for (int i = 0; i < 2; i++) {
    int row = base + i * 8;
    stage16(src + (size_t)(row + r) * ld + ch * 8, ldsB + row * 64);
  }
}

#define MFMAQ(AF, KB, MB)                                                        \
  __builtin_amdgcn_s_setprio(1);                                                 \
  _Pragma("unroll")                                                              \
  for (int m = 0; m < 4; m++)                                                    \
    _Pragma("unroll")                                                            \
    for (int n = 0; n < 4; n++)                                                  \
      acc[(MB) + m][n] = __builtin_amdgcn_mfma_f32_16x16x32_bf16(                \
          AF[m], bfr[(KB) + n], acc[(MB) + m][n], 0, 0, 0);                      \
  __builtin_amdgcn_s_setprio(0);

__device__ __forceinline__ void gemm256(const u16* __restrict__ A, int lda,
                                        const u16* __restrict__ B, int ldb,
                                        int nT, u16* lds, f32x4 acc[8][4]) {
  const int t = threadIdx.x, w = t >> 6, l = t & 63;
  const int wr = w >> 2, wc = w & 3;
  u16* A0 = lds;           u16* B0 = lds + 16384;
  u16* A1 = lds + 32768;   u16* B1 = lds + 49152;

  #pragma unroll
  for (int m = 0; m < 8; m++)
    #pragma unroll
    for (int n = 0; n < 4; n++)
      #pragma unroll
      for (int j = 0; j < 4; j++) acc[m][n][j] = 0.f;

  stageB(B, ldb, 0, B0, w, l);
  stageB(B, ldb, 1, B0, w, l);
  stageA(A, lda, 0, A0, w, l);
  stageA(A, lda, 1, A0, w, l);
  if (nT > 1) stageA(A + 64, lda, 0, A1, w, l);
  asm volatile("s_waitcnt vmcnt(4)" ::: "memory");
  SYNC_POINT()

  const int arow = wr * 128 + (l & 15), hi = l >> 4;
  const int brow = wc * 64 + (l & 15);

  for (int kt = 0; kt < nT; kt++) {
    u16* cA = (kt & 1) ? A1 : A0;
    u16* cB = (kt & 1) ? B1 : B0;
    u16* nA = (kt & 1) ? A0 : A1;
    u16* nB = (kt & 1) ? B0 : B1;
    const u16* An1 = A + (size_t)(kt + 1) * 64;
    const u16* Bn1 = B + (size_t)(kt + 1) * 64;
    const u16* An2 = A + (size_t)(kt + 2) * 64;
    const bool has1 = (kt + 1 < nT), has2 = (kt + 2 < nT);
    bf16x8 af0[4], af1[4], bfr[8];

    // Ph1: read alpha ks0 + B ks0; stage B-h0(t+1)
    #pragma unroll
    for (int m = 0; m < 4; m++) af0[m] = readfrag(cA, arow + m * 16, 0, hi);
    #pragma unroll
    for (int n = 0; n < 4; n++) bfr[n] = readfrag(cB, brow + n * 16, 0, hi);
    if (has1) stageB(Bn1, ldb, 0, nB, w, l);
    SYNC_POINT()
    LGK0()
    MFMAQ(af0, 0, 0)
    SYNC_POINT()

    // Ph2: read alpha ks1 + B ks1; stage B-h1(t+1); counted wait covers
    // beta(t) [Ah1(t), issued Ph4(t-1)] and alpha(t+1) [Ah0(t+1), Ph3(t-1)]
    #pragma unroll
    for (int m = 0; m < 4; m++) af1[m] = readfrag(cA, arow + m * 16, 1, hi);
    #pragma unroll
    for (int n = 0; n < 4; n++) bfr[4 + n] = readfrag(cB, brow + n * 16, 1, hi);
    if (has1) {
      stageB(Bn1, ldb, 1, nB, w, l);
      asm volatile("s_waitcnt vmcnt(4)" ::: "memory");
    } else {
      asm volatile("s_waitcnt vmcnt(0)" ::: "memory");
    }
    SYNC_POINT()
    LGK0()
    MFMAQ(af1, 4, 0)
    SYNC_POINT()

    // Ph3: read beta ks0; stage A-h0(t+2) into alpha of current buffer
    // (all alpha reads completed at Ph2's trailing barrier -> race-free)
    #pragma unroll
    for (int m = 0; m < 4; m++) af0[m] = readfrag(cA, arow + 64 + m * 16, 0, hi);
    if (has2) stageA(An2, lda, 0, cA, w, l);
    SYNC_POINT()
    LGK0()
    MFMAQ(af0, 0, 4)
    SYNC_POINT()

    // Ph4: read beta ks1; stage A-h1(t+1); counted wait covers B(t+1)
    #pragma unroll
    for (int m = 0; m < 4; m++) af1[m] = readfrag(cA, arow + 64 + m * 16, 1, hi);
    if (has1) stageA(An1, lda, 1, nA, w, l);
    if (has1 && has2)  { asm volatile("s_waitcnt vmcnt(4)" ::: "memory"); }
    else if (has1)     { asm volatile("s_waitcnt vmcnt(2)" ::: "memory"); }
    else               { asm volatile("s_waitcnt vmcnt(0)" ::: "memory"); }
    SYNC_POINT()
    LGK0()
    MFMAQ(af1, 4, 4)
    SYNC_POINT()
  }
}

__device__ __forceinline__ void store256_bf16(f32x4 acc[8][4], u16* smem,
                                              u16* dst, int ld) {
  int t = threadIdx.x, w = t >> 6, l = t & 63;
  int wr = w >> 2, wc = w & 3;
  #pragma unroll
  for (int q = 0; q < 4; q++) {
    __syncthreads();
    if (wr == (q >> 1)) {
      int mb = (q & 1) * 4;
      #pragma unroll
      for (int mm = 0; mm < 4; mm++)
        #pragma unroll
        for (int j = 0; j < 4; j++) {
          int row = mm * 16 + (l >> 4) * 4 + j;
          #pragma unroll
          for (int n = 0; n < 4; n++)
            smem[row * 264 + wc * 64 + n * 16 + (l & 15)] = f2bf(acc[mb + mm][n][j]);
        }
    }
    __syncthreads();
    #pragma unroll
    for (int i = 0; i < 4; i++) {
      int idx = i * 512 + t;
      int row = idx >> 5, ch = idx & 31;
      *(u16x8*)(dst + (size_t)(q * 64 + row) * ld + ch * 8) =
          *(const u16x8*)(smem + row * 264 + ch * 8);
    }
  }
}

__global__ __launch_bounds__(512, 2) void gemm_qkv(
    const u16* __restrict__ xb, const u16* __restrict__ Wt,
    u16* __restrict__ qb, u16* __restrict__ kb, u16* __restrict__ vT) {
  __shared__ __align__(16) u16 lds[65536];   // 128 KB
  int z = blockIdx.z;                        // identity mapping (swizzle hurt: r7)
  f32x4 acc[8][4];
  if (z < 2) {
    int m0 = blockIdx.x * 256, n0 = blockIdx.y * 256;
    gemm256(xb + (size_t)m0 * F_, F_,
            Wt + (size_t)z * D_ * F_ + (size_t)n0 * F_, F_, F_ / 64, lds, acc);
    store256_bf16(acc, lds, ((z == 0) ? qb : kb) + (size_t)m0 * D_ + n0, D_);
  } else {
    int d0 = blockIdx.y * 256, s0g = blockIdx.x * 256;
    gemm256(Wt + 2ULL * D_ * F_ + (size_t)d0 * F_, F_,
            xb + (size_t)s0g * F_, F_, F_ / 64, lds, acc);
    int b = s0g >> 11, s0 = s0g & 2047;
    store256_bf16(acc, lds, vT + (size_t)b * D_ * S_ + (size_t)d0 * S_ + s0, S_);
  }
}

// =============== 128x128 / BK=64 / 4-wave engine (PV) ===============
// PACKA=1: A is causal-tile-packed (lda=128, tile stride TELEM_)

template <int PACKA>
__device__ __forceinline__ void gemm128(const u16* __restrict__ A, int lda,
                                        const u16* __restrict__ B, int ldb,
                                        int nT, u16* lds, f32x4 acc[4][4]) {
  const int t = threadIdx.x, w = t >> 6, l = t & 63;
  const int wr = w >> 1, wc = w & 1;
  u16* A0 = lds;          u16* B0 = lds + 8192;
  u16* A1 = lds + 16384;  u16* B1 = lds + 24576;

  auto asrc = [&](int kt) -> const u16* {
    return PACKA ? A + (size_t)(kt >> 1) * TELEM_ + (kt & 1) * 64
                 : A + (size_t)kt * 64;
  };

  #pragma unroll
  for (int m = 0; m < 4; m++)
    #pragma unroll
    for (int n = 0; n < 4; n++)
      #pragma unroll
      for (int j = 0; j < 4; j++) acc[m][n][j] = 0.f;

  auto stg = [&](const u16* src, int ld, int h, u16* dst) {
    int base = h * 64 + w * 16;
    int r = l >> 3, ch = (l & 7) ^ (l >> 3);
    #pragma unroll
    for (int i = 0; i < 2; i++) {
      int row = base + i * 8;
      stage16(src + (size_t)(row + r) * ld + ch * 8, dst + row * 64);
    }
  };

  stg(asrc(0), PACKA ? 128 : lda, 0, A0);
  stg(asrc(0), PACKA ? 128 : lda, 1, A0);
  stg(B, ldb, 0, B0);
  stg(B, ldb, 1, B0);
  if (nT > 1) {
    stg(asrc(1), PACKA ? 128 : lda, 0, A1);
    stg(asrc(1), PACKA ? 128 : lda, 1, A1);
    asm volatile("s_waitcnt vmcnt(4)" ::: "memory");
  } else {
    asm volatile("s_waitcnt vmcnt(0)" ::: "memory");
  }
  SYNC_POINT()

  const int arow = wr * 64 + (l & 15), brow = wc * 64 + (l & 15), hi = l >> 4;

  for (int kt = 0; kt < nT; kt++) {
    u16* cA = (kt & 1) ? A1 : A0;
    u16* cB = (kt & 1) ? B1 : B0;
    u16* nB = (kt & 1) ? B0 : B1;
    const bool has1 = (kt + 1 < nT), has2 = (kt + 2 < nT);
    bf16x8 a0f[4], b0f[4], a1f[4], b1f[4];

    #pragma unroll
    for (int m = 0; m < 4; m++) a0f[m] = readfrag(cA, arow + m * 16, 0, hi);
    #pragma unroll
    for (int n = 0; n < 4; n++) b0f[n] = readfrag(cB, brow + n * 16, 0, hi);
    #pragma unroll
    for (int m = 0; m < 4; m++) a1f[m] = readfrag(cA, arow + m * 16, 1, hi);
    #pragma unroll
    for (int n = 0; n < 4; n++) b1f[n] = readfrag(cB, brow + n * 16, 1, hi);
    if (has1) {
      stg(B + (size_t)(kt + 1) * 64, ldb, 0, nB);
      stg(B + (size_t)(kt + 1) * 64, ldb, 1, nB);
    }
    __builtin_amdgcn_s_setprio(1);
    #pragma unroll
    for (int m = 0; m < 4; m++)
      #pragma unroll
      for (int n = 0; n < 4; n++)
        acc[m][n] = __builtin_amdgcn_mfma_f32_16x16x32_bf16(a0f[m], b0f[n], acc[m][n], 0, 0, 0);
    __builtin_amdgcn_s_setprio(0);
    asm volatile("s_waitcnt lgkmcnt(0)" ::: "memory");
    SYNC_POINT()

    if (has2) {
      stg(asrc(kt + 2), PACKA ? 128 : lda, 0, cA);
      stg(asrc(kt + 2), PACKA ? 128 : lda, 1, cA);
    }
    __builtin_amdgcn_s_setprio(1);
    #pragma unroll
    for (int m = 0; m < 4; m++)
      #pragma unroll
      for (int n = 0; n < 4; n++)
        acc[m][n] = __builtin_amdgcn_mfma_f32_16x16x32_bf16(a1f[m], b1f[n], acc[m][n], 0, 0, 0);
    __builtin_amdgcn_s_setprio(0);
    if (has2)      { asm volatile("s_waitcnt vmcnt(4)" ::: "memory"); }
    else if (has1) { asm volatile("s_waitcnt vmcnt(0)" ::: "memory"); }
    SYNC_POINT()
  }
}

__device__ __forceinline__ void tri_decode(int x, int& mt, int& nt) {
  mt = (int)((sqrtf(8.f * x + 1.f) - 1.f) * 0.5f);
  while ((mt + 1) * (mt + 2) / 2 <= x) mt++;
  while (mt * (mt + 1) / 2 > x) mt--;
  nt = x - mt * (mt + 1) / 2;
}

// ------- scores (er path): 256^2 tiles on gemm256; P = exp(qk/32 + er - 16),
//         written into the 128-packed tri layout (4 sub-tiles per 256-tile) -------
__global__ __launch_bounds__(512, 2) void attn_scores_er(
    const u16* __restrict__ qb, const u16* __restrict__ kb,
    const u16* __restrict__ er, u16* __restrict__ P,
    float* __restrict__ rowsum) {
  __shared__ __align__(16) u16 lds[65536];
  int f = xcd_swz(blockIdx.x + 36 * blockIdx.y, 288);
  int x = f % 36, b = f / 36;
  int MT, NT; tri_decode(x, MT, NT);       // 8x8 causal tri of 256-tiles
  int m0 = MT * 256, n0 = NT * 256;
  f32x4 acc[8][4];
  gemm256(qb + ((size_t)b * S_ + m0) * D_, D_,
          kb + ((size_t)b * S_ + n0) * D_, D_, D_ / 64, lds, acc);
  int t = threadIdx.x, w = t >> 6, l = t & 63;
  int wr = w >> 2, wc = w & 3;
  float* fs = (float*)lds;                 // 64 x 260 f32 staging
  const u16* erb = er + (size_t)b * TRI_ * TELEM_;
  u16* Pb = P + (size_t)b * TRI_ * TELEM_;
  #pragma unroll
  for (int q = 0; q < 4; q++) {
    __syncthreads();
    if (wr == (q >> 1)) {
      int mb = (q & 1) * 4;
      #pragma unroll
      for (int mm = 0; mm < 4; mm++)
        #pragma unroll
        for (int j = 0; j < 4; j++) {
          int row = mm * 16 + (l >> 4) * 4 + j;
          #pragma unroll
          for (int n = 0; n < 4; n++)
            fs[row * 260 + wc * 64 + n * 16 + (l & 15)] = acc[mb + mm][n][j];
        }
    }
    __syncthreads();
    int row = t >> 3, cg = t & 7;          // 64 rows x 8 col-groups of 32
    int rin256 = q * 64 + row;
    int mt128 = 2 * MT + (rin256 >> 7), rin128 = rin256 & 127;
    int nt128 = 2 * NT + (cg >> 2);
    bool valid = (nt128 <= mt128);         // upper-right quadrant of diagonal tiles skipped
    float rsum = 0.f;
    if (valid) {
      size_t sb = (size_t)(mt128 * (mt128 + 1) / 2 + nt128) * TELEM_
                  + (size_t)rin128 * 128 + (cg & 3) * 32;
      const u16* et = erb + sb;
      u16* pt = Pb + sb;
      const float* fsc = fs + row * 260 + cg * 32;
      #pragma unroll
      for (int cc = 0; cc < 4; cc++) {
        int ch = (cg + cc) & 3;            // stagger LDS chunk order
        f32x4 q0 = *(const f32x4*)(fsc + ch * 8);
        f32x4 q1 = *(const f32x4*)(fsc + ch * 8 + 4);
        u16x8 e8 = *(const u16x8*)(et + ch * 8);
        u16x8 o;
        #pragma unroll
        for (int k = 0; k < 8; k++) {
          float qk = (k < 4) ? q0[k] : q1[k - 4];
          float e = __expf(fmaf(qk, 0.03125f, bf2f(e8[k]) - 16.f));
          u16 pb = f2bf(e); o[k] = pb; rsum += bf2f(pb);
        }
        *(u16x8*)(pt + ch * 8) = o;
      }
    }
    rsum += __shfl_xor(rsum, 1);
    rsum += __shfl_xor(rsum, 2);
    rsum += __shfl_xor(rsum, 4);
    if ((t & 7) == 0) atomicAdd(&rowsum[b * S_ + m0 + rin256], rsum);
  }
}

// ------- scores (fallback): 128^2 tiles, reads r_mat/pm/rs_r; tile-packed P -------
__global__ __launch_bounds__(256, 2) void attn_scores_rm(
    const u16* __restrict__ qb, const u16* __restrict__ kb,
    const float* __restrict__ r_mat, const float* __restrict__ pm,
    const float* __restrict__ rs_r, u16* __restrict__ P,
    float* __restrict__ rowsum) {
  __shared__ __align__(16) u16 lds[32768];
  int f = xcd_swz(blockIdx.x + 136 * blockIdx.y, 1088);
  int x = f % 136, b = f / 136;
  int mt, nt; tri_decode(x, mt, nt);
  int m0 = mt * 128, n0 = nt * 128;
  f32x4 acc[4][4];
  gemm128<0>(qb + ((size_t)b * S_ + m0) * D_, D_,
             kb + ((size_t)b * S_ + n0) * D_, D_, D_ / 64, lds, acc);
  int t = threadIdx.x, w = t >> 6, l = t & 63;
  int wr = w >> 1, wc = w & 1;
  float* fs = (float*)lds;
  const float* rb = r_mat + (size_t)b * S_ * S_;
  const float* pmp = pm + (size_t)b * S_ + n0;
  size_t tbase = (size_t)(b * TRI_ + mt * (mt + 1) / 2 + nt) * TELEM_;
  #pragma unroll
  for (int h = 0; h < 2; h++) {
    __syncthreads();
    if (wr == h) {
      #pragma unroll
      for (int m = 0; m < 4; m++)
        #pragma unroll
        for (int j = 0; j < 4; j++) {
          int row = m * 16 + (l >> 4) * 4 + j;
          #pragma unroll
          for (int n = 0; n < 4; n++)
            fs[row * 132 + wc * 64 + n * 16 + (l & 15)] = acc[m][n][j];
        }
    }
    __syncthreads();
    int row = t >> 2, cg = t & 3;
    int srow = m0 + h * 64 + row;
    float invr = 1.f / rs_r[b * S_ + srow];
    const float* rrow = rb + (size_t)srow * S_ + n0 + cg * 32;
    u16* pt = P + tbase + (size_t)(h * 64 + row) * 128 + cg * 32;
    const float* fsc = fs + row * 132 + cg * 32;
    float rsum = 0.f;
    #pragma unroll
    for (int cc = 0; cc < 4; cc++) {
      int ch = (cg + cc) & 3;
      f32x4 q0 = *(const f32x4*)(fsc + ch * 8);
      f32x4 q1 = *(const f32x4*)(fsc + ch * 8 + 4);
      f32x4 r0 = *(const f32x4*)(rrow + ch * 8);
      f32x4 r1 = *(const f32x4*)(rrow + ch * 8 + 4);
      f32x4 p0 = *(const f32x4*)(pmp + cg * 32 + ch * 8);
      f32x4 p1 = *(const f32x4*)(pmp + cg * 32 + ch * 8 + 4);
      u16x8 o;
      #pragma unroll
      for (int k = 0; k < 8; k++) {
        int tc = n0 + cg * 32 + ch * 8 + k;
        float rv = (k < 4) ? r0[k] : r1[k - 4];
        float pmv = (k < 4) ? p0[k] : p1[k - 4];
        float qk = (k < 4) ? q0[k] : q1[k - 4];
        bool keep = (tc <= srow) && (pmv != 0.f);
        float rsm = __expf(rv - 16.f) * invr;
        float e = keep ? __expf(fmaf(qk, 0.03125f, rsm - 16.f)) : 0.f;
        u16 pb = f2bf(e); o[k] = pb; rsum += bf2f(pb);
      }
      *(u16x8*)(pt + ch * 8) = o;
    }
    rsum += __shfl_xor(rsum, 1);
    rsum += __shfl_xor(rsum, 2);
    if ((t & 3) == 0) atomicAdd(&rowsum[b * S_ + srow], rsum);
  }
}

// ------- PV: out = (P @ V) / rowsum; paired tiles (15-mtp, mtp) for balance -------
__global__ __launch_bounds__(256, 2) void attn_pv(
    const u16* __restrict__ P, const u16* __restrict__ vT,
    const float* __restrict__ rowsum, float* __restrict__ out) {
  __shared__ __align__(16) u16 lds[32768];
  int f = xcd_swz(blockIdx.x + 8 * blockIdx.y + 64 * blockIdx.z, 512);
  int mtp = f & 7, dt = (f >> 3) & 7, b = f >> 6;
  for (int hf = 0; hf < 2; hf++) {
    int mt = hf ? mtp : (15 - mtp);        // heavy tile first; cost sum = 17 const
    int m0 = mt * 128, n0 = dt * 128;
    int nT = 2 * (mt + 1);
    f32x4 acc[4][4];
    gemm128<1>(P + (size_t)(b * TRI_ + mt * (mt + 1) / 2) * TELEM_, 128,
               vT + ((size_t)b * D_ + n0) * S_, S_, nT, lds, acc);
    int t = threadIdx.x, w = t >> 6, l = t & 63;
    int wr = w >> 1, wc = w & 1;
    float* fs = (float*)lds;
    #pragma unroll
    for (int h = 0; h < 2; h++) {
      __syncthreads();
      if (wr == h) {
        #pragma unroll
        for (int m = 0; m < 4; m++)
          #pragma unroll
          for (int j = 0; j < 4; j++) {
            int row = m * 16 + (l >> 4) * 4 + j;
            float inv = 1.f / rowsum[b * S_ + m0 + h * 64 + row];
            #pragma unroll
            for (int n = 0; n < 4; n++)
              fs[row * 132 + wc * 64 + n * 16 + (l & 15)] = acc[m][n][j] * inv;
          }
      }
      __syncthreads();
      #pragma unroll
      for (int i = 0; i < 8; i++) {
        int idx = i * 256 + t;
        int row = idx >> 5, c4 = (idx & 31) << 2;
        *(float4*)(out + ((size_t)b * S_ + m0 + h * 64 + row) * D_ + n0 + c4) =
            *(const float4*)(fs + row * 132 + c4);
      }
    }
    __syncthreads();   // protect LDS from next tile's prologue DMA
  }
}

// ---------------- launch ----------------
extern "C" void kernel_launch(void* const* d_in, const int* in_sizes, int n_in,
                              void* d_out, int out_size, void* d_ws, size_t ws_size,
                              hipStream_t stream) {
  const float* x     = (const float*)d_in[0];
  const float* r_mat = (const float*)d_in[1];
  const float* pm    = (const float*)d_in[3];
  const float* Wq    = (const float*)d_in[4];
  const float* Wk    = (const float*)d_in[5];
  const float* Wv    = (const float*)d_in[6];
  float* out = (float*)d_out;
  char* ws = (char*)d_ws;

  const size_t PK = (size_t)B_ * TRI_ * TELEM_ * 2;   // 37,355,520 bytes
  u16*   qb     = (u16*)(ws + 0);
  u16*   kb     = (u16*)(ws + 33554432ULL);
  u16*   vT     = (u16*)(ws + 67108864ULL);
  float* rowsum = (float*)(ws + 100663296ULL);
  float* rs_r   = (float*)(ws + 100728832ULL);
  u16*   xb     = (u16*)(ws + 100794368ULL);            // dead after gemm_qkv
  u16*   Wt     = (u16*)(ws + 134348800ULL);            // dead after gemm_qkv
  u16*   er     = (u16*)(ws + 100794368ULL);            // reuses xb region
  bool use_er   = ws_size >= 100794368ULL + 2 * PK;     // 175,505,408
  u16*   P      = use_er ? (u16*)(ws + 100794368ULL + PK)
                         : (u16*)(ws + 100794368ULL);

  prep<<<dim3(5120), dim3(256), 0, stream>>>(x, Wq, Wk, Wv, xb, Wt);
  if (!use_er)
    r_rowsum<<<dim3(B_ * S_), dim3(256), 0, stream>>>(r_mat, pm, rs_r);
  gemm_qkv<<<dim3(64, 4, 3), dim3(512), 0, stream>>>(xb, Wt, qb, kb, vT);
  if (use_er) {
    er_pass<<<dim3(B_ * S_), dim3(256), 0, stream>>>(r_mat, pm, er, rowsum);
    attn_scores_er<<<dim3(36, 8), dim3(512), 0, stream>>>(qb, kb, er, P, rowsum);
  } else {
    hipMemsetAsync(rowsum, 0, B_ * S_ * sizeof(float), stream);
    attn_scores_rm<<<dim3(136, 8), dim3(256), 0, stream>>>(qb, kb, r_mat, pm, rs_r, P, rowsum);
  }
  attn_pv<<<dim3(8, 8, 8), dim3(256), 0, stream>>>(P, vT, rowsum, out);
}

// Round 14
// 267.609 us; speedup vs baseline: 1.0492x; 1.0492x over previous
//
#include <hip/hip_runtime.h>
#include <hip/hip_bf16.h>

#define B_ 8
#define S_ 2048
#define F_ 1024
#define D_ 1024
#define TRI_ 136            // 16*17/2 causal tiles per batch (128x128)
#define TELEM_ 16384        // elems per 128x128 tile

typedef unsigned short u16;
typedef float f32x4 __attribute__((ext_vector_type(4)));
typedef __bf16 bf16x8 __attribute__((ext_vector_type(8)));
typedef unsigned short u16x8 __attribute__((ext_vector_type(8)));

__device__ __forceinline__ u16 f2bf(float f) {
  union { float f; unsigned u; } v; v.f = f;
  unsigned r = v.u + 0x7fff + ((v.u >> 16) & 1);
  return (u16)(r >> 16);
}
__device__ __forceinline__ float bf2f(u16 b) {
  union { unsigned u; float f; } v; v.u = ((unsigned)b) << 16;
  return v.f;
}

__device__ __forceinline__ void stage16(const u16* g, u16* l) {
  __builtin_amdgcn_global_load_lds(
      (const __attribute__((address_space(1))) void*)g,
      (__attribute__((address_space(3))) void*)l, 16, 0, 0);
}

// bijective XCD-chunk swizzle: n must be divisible by 8
__device__ __forceinline__ int xcd_swz(int f, int n) {
  int per = n >> 3;
  return (f & 7) * per + (f >> 3);
}

// ---------------- prep: fused cast_x + transW ----------------

__global__ __launch_bounds__(256) void prep(const float* __restrict__ x,
                                            const float* __restrict__ Wq,
                                            const float* __restrict__ Wk,
                                            const float* __restrict__ Wv,
                                            u16* __restrict__ xb,
                                            u16* __restrict__ Wt) {
  __shared__ float tile[32][33];
  if (blockIdx.x < 2048) {
    int n4 = (B_ * S_ * F_) / 4;
    for (int i = blockIdx.x * 256 + threadIdx.x; i < n4; i += 2048 * 256) {
      float4 v = ((const float4*)x)[i];
      ushort4 o;
      o.x = f2bf(v.x); o.y = f2bf(v.y); o.z = f2bf(v.z); o.w = f2bf(v.w);
      ((ushort4*)xb)[i] = o;
    }
  } else {
    int f = blockIdx.x - 2048;     // 0..3071
    int z = f >> 10;
    int f2 = f & 1023;
    int f0 = (f2 >> 5) * 32, d0 = (f2 & 31) * 32;
    const float* W = (z == 0) ? Wq : ((z == 1) ? Wk : Wv);
    int tx = threadIdx.x & 31, ty = threadIdx.x >> 5;
    for (int i = 0; i < 4; i++)
      tile[ty + i * 8][tx] = W[(size_t)(f0 + ty + i * 8) * D_ + d0 + tx];
    __syncthreads();
    u16* o = Wt + (size_t)z * D_ * F_;
    for (int i = 0; i < 4; i++)
      o[(size_t)(d0 + ty + i * 8) * F_ + f0 + tx] = f2bf(tile[tx][ty + i * 8]);
  }
}

// er = tile-packed bf16 r-softmax with mask sentinel; also zeroes rowsum
__global__ __launch_bounds__(256) void er_pass(const float* __restrict__ r,
                                               const float* __restrict__ pm,
                                               u16* __restrict__ er,
                                               float* __restrict__ rowsum) {
  int row = blockIdx.x;            // b*S + s
  int b = row >> 11, s = row & 2047;
  if (threadIdx.x == 0) rowsum[row] = 0.f;
  const float4* rp = (const float4*)(r + (size_t)row * S_);
  const float4* pp = (const float4*)(pm + (size_t)b * S_);
  int nk = (s >> 2) + 1;           // quads containing kept cols
  int nw = ((s >> 7) + 1) << 5;    // write quads (128-rounded extent / 4)
  float4 ev[8];
  float acc = 0.f;
  #pragma unroll
  for (int it = 0; it < 8; it++) {
    int i = threadIdx.x + it * 256;
    if (i < nk) {
      float4 rv = rp[i], pv = pp[i];
      int t0 = i << 2;
      float4 e;
      #pragma unroll
      for (int j = 0; j < 4; j++) {
        bool keep = (t0 + j <= s) && ((&pv.x)[j] != 0.f);
        (&e.x)[j] = keep ? __expf((&rv.x)[j] - 16.f) : 0.f;
        acc += (&e.x)[j];
      }
      ev[it] = e;
    }
  }
  for (int off = 1; off < 64; off <<= 1) acc += __shfl_xor(acc, off);
  __shared__ float wsum[4];
  int lane = threadIdx.x & 63, w = threadIdx.x >> 6;
  if (lane == 0) wsum[w] = acc;
  __syncthreads();
  float invr = 1.f / (wsum[0] + wsum[1] + wsum[2] + wsum[3]);
  int c = s >> 7, rin = s & 127;
  u16* tb = er + (size_t)(b * TRI_ + c * (c + 1) / 2) * TELEM_ + rin * 128;
  #pragma unroll
  for (int it = 0; it < 8; it++) {
    int i = threadIdx.x + it * 256;
    if (i < nw) {
      int t0 = i << 2;
      float4 pv = pp[i];
      ushort4 o;
      #pragma unroll
      for (int j = 0; j < 4; j++) {
        bool keep = (t0 + j <= s) && ((&pv.x)[j] != 0.f);
        float val = keep ? (&ev[it].x)[j] * invr : -1e9f;
        (&o.x)[j] = f2bf(val);
      }
      *(ushort4*)(tb + (size_t)(t0 >> 7) * TELEM_ + (t0 & 127)) = o;
    }
  }
}

// fallback row-sum only (when ws too small for er)
__global__ __launch_bounds__(256) void r_rowsum(const float* __restrict__ r,
                                                const float* __restrict__ pm,
                                                float* __restrict__ rs) {
  int row = blockIdx.x;
  int b = row >> 11, s = row & 2047;
  const float4* rp = (const float4*)(r + (size_t)row * S_);
  const float4* pp = (const float4*)(pm + (size_t)b * S_);
  int nv = (s >> 2) + 1;
  float acc = 0.f;
  for (int i = threadIdx.x; i < nv; i += 256) {
    float4 rv = rp[i];
    float4 pv = pp[i];
    int t0 = i << 2;
    #pragma unroll
    for (int j = 0; j < 4; j++) {
      int t = t0 + j;
      if (t <= s && (&pv.x)[j] != 0.f) acc += __expf((&rv.x)[j] - 16.f);
    }
  }
  for (int off = 1; off < 64; off <<= 1) acc += __shfl_xor(acc, off);
  __shared__ float wsum[4];
  int lane = threadIdx.x & 63, w = threadIdx.x >> 6;
  if (lane == 0) wsum[w] = acc;
  __syncthreads();
  if (threadIdx.x == 0) rs[row] = wsum[0] + wsum[1] + wsum[2] + wsum[3];
}

// ---------------- shared GEMM helpers ----------------

__device__ __forceinline__ bf16x8 readfrag(const u16* lds, int row, int ks, int hi) {
  int c = ((ks << 6) + (hi << 4)) ^ ((row & 7) << 4);
  return *(const bf16x8*)((const char*)lds + row * 128 + c);
}

#define SYNC_POINT()                                                             \
  __builtin_amdgcn_sched_barrier(0);                                             \
  __builtin_amdgcn_s_barrier();                                                  \
  __builtin_amdgcn_sched_barrier(0);

// =============== 256x256 / BK=64 / 8-wave engine ===============
// r8/r12-proven configuration: LDS-staged A and B, 4 phases, 2 barriers + 2
// counted vmcnt(4) per K-tile, intra-tile read-ahead. 97us / 46% MfmaUtil.
// (r13's m201-style 8-barrier variant regressed to 109us / 39% — reverted.)

__device__ __forceinline__ void stageA(const u16* __restrict__ src, int ld, int h,
                                       u16* ldsA, int w, int l) {
  int base = ((w >> 2) * 128) + h * 64 + ((w & 3) * 16);
  int r = l >> 3, ch = (l & 7) ^ (l >> 3);
  #pragma unroll
  for (int i = 0; i < 2; i++) {
    int row = base + i * 8;
    stage16(src + (size_t)(row + r) * ld + ch * 8, ldsA + row * 64);
  }
}
__device__ __forceinline__ void stageB(const u16* __restrict__ src, int ld, int h,
                                       u16* ldsB, int w, int l) {
  int base = h * 128 + w * 16;
  int r = l >> 3, ch = (l & 7) ^ (l >> 3);
  #pragma unroll
  for (int i = 0; i < 2; i++) {
    int row = base + i * 8;
    stage16(src + (size_t)(row + r) * ld + ch * 8, ldsB + row * 64);
  }
}

#define MFMAQ(AF, KB, MB)                                                        \
  __builtin_amdgcn_s_setprio(1);                                                 \
  _Pragma("unroll")                                                              \
  for (int m = 0; m < 4; m++)                                                    \
    _Pragma("unroll")                                                            \
    for (int n = 0; n < 4; n++)                                                  \
      acc[(MB) + m][n] = __builtin_amdgcn_mfma_f32_16x16x32_bf16(                \
          AF[m], bfr[(KB) + n], acc[(MB) + m][n], 0, 0, 0);                      \
  __builtin_amdgcn_s_setprio(0);

__device__ __forceinline__ void gemm256(const u16* __restrict__ A, int lda,
                                        const u16* __restrict__ B, int ldb,
                                        int nT, u16* lds, f32x4 acc[8][4]) {
  const int t = threadIdx.x, w = t >> 6, l = t & 63;
  const int wr = w >> 2, wc = w & 3;
  u16* A0 = lds;           u16* B0 = lds + 16384;
  u16* A1 = lds + 32768;   u16* B1 = lds + 49152;

  #pragma unroll
  for (int m = 0; m < 8; m++)
    #pragma unroll
    for (int n = 0; n < 4; n++)
      #pragma unroll
      for (int j = 0; j < 4; j++) acc[m][n][j] = 0.f;

  stageB(B, ldb, 0, B0, w, l);
  stageB(B, ldb, 1, B0, w, l);
  stageA(A, lda, 0, A0, w, l);
  stageA(A, lda, 1, A0, w, l);
  if (nT > 1) stageA(A + 64, lda, 0, A1, w, l);
  asm volatile("s_waitcnt vmcnt(4)" ::: "memory");
  SYNC_POINT()

  const int arow = wr * 128 + (l & 15), hi = l >> 4;
  const int brow = wc * 64 + (l & 15);

  for (int kt = 0; kt < nT; kt++) {
    u16* cA = (kt & 1) ? A1 : A0;
    u16* cB = (kt & 1) ? B1 : B0;
    u16* nA = (kt & 1) ? A0 : A1;
    u16* nB = (kt & 1) ? B0 : B1;
    const u16* An1 = A + (size_t)(kt + 1) * 64;
    const u16* Bn1 = B + (size_t)(kt + 1) * 64;
    const u16* An2 = A + (size_t)(kt + 2) * 64;
    const bool has1 = (kt + 1 < nT), has2 = (kt + 2 < nT);
    bf16x8 af0[4], af1[4], bfr[8];

    // P1: read ALL alpha frags + both B k-slices; stage B-h0(t+1); MFMA q1
    #pragma unroll
    for (int m = 0; m < 4; m++) af0[m] = readfrag(cA, arow + m * 16, 0, hi);
    #pragma unroll
    for (int n = 0; n < 4; n++) bfr[n] = readfrag(cB, brow + n * 16, 0, hi);
    #pragma unroll
    for (int m = 0; m < 4; m++) af1[m] = readfrag(cA, arow + m * 16, 1, hi);
    #pragma unroll
    for (int n = 0; n < 4; n++) bfr[4 + n] = readfrag(cB, brow + n * 16, 1, hi);
    if (has1) stageB(Bn1, ldb, 0, nB, w, l);
    MFMAQ(af0, 0, 0)

    // P2: stage B-h1(t+1); counted wait; barrier; MFMA q2 pre-loaded
    if (has1) {
      stageB(Bn1, ldb, 1, nB, w, l);
      asm volatile("s_waitcnt vmcnt(4)" ::: "memory");
    } else {
      asm volatile("s_waitcnt vmcnt(0)" ::: "memory");
    }
    SYNC_POINT()
    MFMAQ(af1, 4, 0)

    // P3: read BOTH beta k-slices; stage A-alpha(t+2) into freed region; MFMA q3
    #pragma unroll
    for (int m = 0; m < 4; m++) af0[m] = readfrag(cA, arow + 64 + m * 16, 0, hi);
    #pragma unroll
    for (int m = 0; m < 4; m++) af1[m] = readfrag(cA, arow + 64 + m * 16, 1, hi);
    if (has2) stageA(An2, lda, 0, cA, w, l);
    MFMAQ(af0, 0, 4)

    // P4: stage A-beta(t+1); counted wait; barrier; MFMA q4 pre-loaded
    if (has1) stageA(An1, lda, 1, nA, w, l);
    if (has1 && has2)  { asm volatile("s_waitcnt vmcnt(4)" ::: "memory"); }
    else if (has1)     { asm volatile("s_waitcnt vmcnt(2)" ::: "memory"); }
    else               { asm volatile("s_waitcnt vmcnt(0)" ::: "memory"); }
    SYNC_POINT()
    MFMAQ(af1, 4, 4)
  }
}

__device__ __forceinline__ void store256_bf16(f32x4 acc[8][4], u16* smem,
                                              u16* dst, int ld) {
  int t = threadIdx.x, w = t >> 6, l = t & 63;
  int wr = w >> 2, wc = w & 3;
  #pragma unroll
  for (int q = 0; q < 4; q++) {
    __syncthreads();
    if (wr == (q >> 1)) {
      int mb = (q & 1) * 4;
      #pragma unroll
      for (int mm = 0; mm < 4; mm++)
        #pragma unroll
        for (int j = 0; j < 4; j++) {
          int row = mm * 16 + (l >> 4) * 4 + j;
          #pragma unroll
          for (int n = 0; n < 4; n++)
            smem[row * 264 + wc * 64 + n * 16 + (l & 15)] = f2bf(acc[mb + mm][n][j]);
        }
    }
    __syncthreads();
    #pragma unroll
    for (int i = 0; i < 4; i++) {
      int idx = i * 512 + t;
      int row = idx >> 5, ch = idx & 31;
      *(u16x8*)(dst + (size_t)(q * 64 + row) * ld + ch * 8) =
          *(const u16x8*)(smem + row * 264 + ch * 8);
    }
  }
}

__global__ __launch_bounds__(512, 2) void gemm_qkv(
    const u16* __restrict__ xb, const u16* __restrict__ Wt,
    u16* __restrict__ qb, u16* __restrict__ kb, u16* __restrict__ vT) {
  __shared__ __align__(16) u16 lds[65536];   // 128 KB
  int z = blockIdx.z;                        // identity mapping (swizzle hurt: r7)
  f32x4 acc[8][4];
  if (z < 2) {
    int m0 = blockIdx.x * 256, n0 = blockIdx.y * 256;
    gemm256(xb + (size_t)m0 * F_, F_,
            Wt + (size_t)z * D_ * F_ + (size_t)n0 * F_, F_, F_ / 64, lds, acc);
    store256_bf16(acc, lds, ((z == 0) ? qb : kb) + (size_t)m0 * D_ + n0, D_);
  } else {
    int d0 = blockIdx.y * 256, s0g = blockIdx.x * 256;
    gemm256(Wt + 2ULL * D_ * F_ + (size_t)d0 * F_, F_,
            xb + (size_t)s0g * F_, F_, F_ / 64, lds, acc);
    int b = s0g >> 11, s0 = s0g & 2047;
    store256_bf16(acc, lds, vT + (size_t)b * D_ * S_ + (size_t)d0 * S_ + s0, S_);
  }
}

// =============== 128x128 / BK=64 / 4-wave engine (PV) ===============
// PACKA=1: A is causal-tile-packed (lda=128, tile stride TELEM_)

template <int PACKA>
__device__ __forceinline__ void gemm128(const u16* __restrict__ A, int lda,
                                        const u16* __restrict__ B, int ldb,
                                        int nT, u16* lds, f32x4 acc[4][4]) {
  const int t = threadIdx.x, w = t >> 6, l = t & 63;
  const int wr = w >> 1, wc = w & 1;
  u16* A0 = lds;          u16* B0 = lds + 8192;
  u16* A1 = lds + 16384;  u16* B1 = lds + 24576;

  auto asrc = [&](int kt) -> const u16* {
    return PACKA ? A + (size_t)(kt >> 1) * TELEM_ + (kt & 1) * 64
                 : A + (size_t)kt * 64;
  };

  #pragma unroll
  for (int m = 0; m < 4; m++)
    #pragma unroll
    for (int n = 0; n < 4; n++)
      #pragma unroll
      for (int j = 0; j < 4; j++) acc[m][n][j] = 0.f;

  auto stg = [&](const u16* src, int ld, int h, u16* dst) {
    int base = h * 64 + w * 16;
    int r = l >> 3, ch = (l & 7) ^ (l >> 3);
    #pragma unroll
    for (int i = 0; i < 2; i++) {
      int row = base + i * 8;
      stage16(src + (size_t)(row + r) * ld + ch * 8, dst + row * 64);
    }
  };

  stg(asrc(0), PACKA ? 128 : lda, 0, A0);
  stg(asrc(0), PACKA ? 128 : lda, 1, A0);
  stg(B, ldb, 0, B0);
  stg(B, ldb, 1, B0);
  if (nT > 1) {
    stg(asrc(1), PACKA ? 128 : lda, 0, A1);
    stg(asrc(1), PACKA ? 128 : lda, 1, A1);
    asm volatile("s_waitcnt vmcnt(4)" ::: "memory");
  } else {
    asm volatile("s_waitcnt vmcnt(0)" ::: "memory");
  }
  SYNC_POINT()

  const int arow = wr * 64 + (l & 15), brow = wc * 64 + (l & 15), hi = l >> 4;

  for (int kt = 0; kt < nT; kt++) {
    u16* cA = (kt & 1) ? A1 : A0;
    u16* cB = (kt & 1) ? B1 : B0;
    u16* nB = (kt & 1) ? B0 : B1;
    const bool has1 = (kt + 1 < nT), has2 = (kt + 2 < nT);
    bf16x8 a0f[4], b0f[4], a1f[4], b1f[4];

    #pragma unroll
    for (int m = 0; m < 4; m++) a0f[m] = readfrag(cA, arow + m * 16, 0, hi);
    #pragma unroll
    for (int n = 0; n < 4; n++) b0f[n] = readfrag(cB, brow + n * 16, 0, hi);
    #pragma unroll
    for (int m = 0; m < 4; m++) a1f[m] = readfrag(cA, arow + m * 16, 1, hi);
    #pragma unroll
    for (int n = 0; n < 4; n++) b1f[n] = readfrag(cB, brow + n * 16, 1, hi);
    if (has1) {
      stg(B + (size_t)(kt + 1) * 64, ldb, 0, nB);
      stg(B + (size_t)(kt + 1) * 64, ldb, 1, nB);
    }
    __builtin_amdgcn_s_setprio(1);
    #pragma unroll
    for (int m = 0; m < 4; m++)
      #pragma unroll
      for (int n = 0; n < 4; n++)
        acc[m][n] = __builtin_amdgcn_mfma_f32_16x16x32_bf16(a0f[m], b0f[n], acc[m][n], 0, 0, 0);
    __builtin_amdgcn_s_setprio(0);
    asm volatile("s_waitcnt lgkmcnt(0)" ::: "memory");
    SYNC_POINT()

    if (has2) {
      stg(asrc(kt + 2), PACKA ? 128 : lda, 0, cA);
      stg(asrc(kt + 2), PACKA ? 128 : lda, 1, cA);
    }
    __builtin_amdgcn_s_setprio(1);
    #pragma unroll
    for (int m = 0; m < 4; m++)
      #pragma unroll
      for (int n = 0; n < 4; n++)
        acc[m][n] = __builtin_amdgcn_mfma_f32_16x16x32_bf16(a1f[m], b1f[n], acc[m][n], 0, 0, 0);
    __builtin_amdgcn_s_setprio(0);
    if (has2)      { asm volatile("s_waitcnt vmcnt(4)" ::: "memory"); }
    else if (has1) { asm volatile("s_waitcnt vmcnt(0)" ::: "memory"); }
    SYNC_POINT()
  }
}

__device__ __forceinline__ void tri_decode(int x, int& mt, int& nt) {
  mt = (int)((sqrtf(8.f * x + 1.f) - 1.f) * 0.5f);
  while ((mt + 1) * (mt + 2) / 2 <= x) mt++;
  while (mt * (mt + 1) / 2 > x) mt--;
  nt = x - mt * (mt + 1) / 2;
}

// ------- scores (er path): 256^2 tiles on gemm256; P = exp(qk/32 + er - 16),
//         written into the 128-packed tri layout (4 sub-tiles per 256-tile) -------
__global__ __launch_bounds__(512, 2) void attn_scores_er(
    const u16* __restrict__ qb, const u16* __restrict__ kb,
    const u16* __restrict__ er, u16* __restrict__ P,
    float* __restrict__ rowsum) {
  __shared__ __align__(16) u16 lds[65536];
  int f = xcd_swz(blockIdx.x + 36 * blockIdx.y, 288);
  int x = f % 36, b = f / 36;
  int MT, NT; tri_decode(x, MT, NT);       // 8x8 causal tri of 256-tiles
  int m0 = MT * 256, n0 = NT * 256;
  f32x4 acc[8][4];
  gemm256(qb + ((size_t)b * S_ + m0) * D_, D_,
          kb + ((size_t)b * S_ + n0) * D_, D_, D_ / 64, lds, acc);
  int t = threadIdx.x, w = t >> 6, l = t & 63;
  int wr = w >> 2, wc = w & 3;
  float* fs = (float*)lds;                 // 64 x 260 f32 staging
  const u16* erb = er + (size_t)b * TRI_ * TELEM_;
  u16* Pb = P + (size_t)b * TRI_ * TELEM_;
  #pragma unroll
  for (int q = 0; q < 4; q++) {
    __syncthreads();
    if (wr == (q >> 1)) {
      int mb = (q & 1) * 4;
      #pragma unroll
      for (int mm = 0; mm < 4; mm++)
        #pragma unroll
        for (int j = 0; j < 4; j++) {
          int row = mm * 16 + (l >> 4) * 4 + j;
          #pragma unroll
          for (int n = 0; n < 4; n++)
            fs[row * 260 + wc * 64 + n * 16 + (l & 15)] = acc[mb + mm][n][j];
        }
    }
    __syncthreads();
    int row = t >> 3, cg = t & 7;          // 64 rows x 8 col-groups of 32
    int rin256 = q * 64 + row;
    int mt128 = 2 * MT + (rin256 >> 7), rin128 = rin256 & 127;
    int nt128 = 2 * NT + (cg >> 2);
    bool valid = (nt128 <= mt128);         // upper-right quadrant of diagonal tiles skipped
    float rsum = 0.f;
    if (valid) {
      size_t sb = (size_t)(mt128 * (mt128 + 1) / 2 + nt128) * TELEM_
                  + (size_t)rin128 * 128 + (cg & 3) * 32;
      const u16* et = erb + sb;
      u16* pt = Pb + sb;
      const float* fsc = fs + row * 260 + cg * 32;
      #pragma unroll
      for (int cc = 0; cc < 4; cc++) {
        int ch = (cg + cc) & 3;            // stagger LDS chunk order
        f32x4 q0 = *(const f32x4*)(fsc + ch * 8);
        f32x4 q1 = *(const f32x4*)(fsc + ch * 8 + 4);
        u16x8 e8 = *(const u16x8*)(et + ch * 8);
        u16x8 o;
        #pragma unroll
        for (int k = 0; k < 8; k++) {
          float qk = (k < 4) ? q0[k] : q1[k - 4];
          float e = __expf(fmaf(qk, 0.03125f, bf2f(e8[k]) - 16.f));
          u16 pb = f2bf(e); o[k] = pb; rsum += bf2f(pb);
        }
        *(u16x8*)(pt + ch * 8) = o;
      }
    }
    rsum += __shfl_xor(rsum, 1);
    rsum += __shfl_xor(rsum, 2);
    rsum += __shfl_xor(rsum, 4);
    if ((t & 7) == 0) atomicAdd(&rowsum[b * S_ + m0 + rin256], rsum);
  }
}

// ------- scores (fallback): 128^2 tiles, reads r_mat/pm/rs_r; tile-packed P -------
__global__ __launch_bounds__(256, 2) void attn_scores_rm(
    const u16* __restrict__ qb, const u16* __restrict__ kb,
    const float* __restrict__ r_mat, const float* __restrict__ pm,
    const float* __restrict__ rs_r, u16* __restrict__ P,
    float* __restrict__ rowsum) {
  __shared__ __align__(16) u16 lds[32768];
  int f = xcd_swz(blockIdx.x + 136 * blockIdx.y, 1088);
  int x = f % 136, b = f / 136;
  int mt, nt; tri_decode(x, mt, nt);
  int m0 = mt * 128, n0 = nt * 128;
  f32x4 acc[4][4];
  gemm128<0>(qb + ((size_t)b * S_ + m0) * D_, D_,
             kb + ((size_t)b * S_ + n0) * D_, D_, D_ / 64, lds, acc);
  int t = threadIdx.x, w = t >> 6, l = t & 63;
  int wr = w >> 1, wc = w & 1;
  float* fs = (float*)lds;
  const float* rb = r_mat + (size_t)b * S_ * S_;
  const float* pmp = pm + (size_t)b * S_ + n0;
  size_t tbase = (size_t)(b * TRI_ + mt * (mt + 1) / 2 + nt) * TELEM_;
  #pragma unroll
  for (int h = 0; h < 2; h++) {
    __syncthreads();
    if (wr == h) {
      #pragma unroll
      for (int m = 0; m < 4; m++)
        #pragma unroll
        for (int j = 0; j < 4; j++) {
          int row = m * 16 + (l >> 4) * 4 + j;
          #pragma unroll
          for (int n = 0; n < 4; n++)
            fs[row * 132 + wc * 64 + n * 16 + (l & 15)] = acc[m][n][j];
        }
    }
    __syncthreads();
    int row = t >> 2, cg = t & 3;
    int srow = m0 + h * 64 + row;
    float invr = 1.f / rs_r[b * S_ + srow];
    const float* rrow = rb + (size_t)srow * S_ + n0 + cg * 32;
    u16* pt = P + tbase + (size_t)(h * 64 + row) * 128 + cg * 32;
    const float* fsc = fs + row * 132 + cg * 32;
    float rsum = 0.f;
    #pragma unroll
    for (int cc = 0; cc < 4; cc++) {
      int ch = (cg + cc) & 3;
      f32x4 q0 = *(const f32x4*)(fsc + ch * 8);
      f32x4 q1 = *(const f32x4*)(fsc + ch * 8 + 4);
      f32x4 r0 = *(const f32x4*)(rrow + ch * 8);
      f32x4 r1 = *(const f32x4*)(rrow + ch * 8 + 4);
      f32x4 p0 = *(const f32x4*)(pmp + cg * 32 + ch * 8);
      f32x4 p1 = *(const f32x4*)(pmp + cg * 32 + ch * 8 + 4);
      u16x8 o;
      #pragma unroll
      for (int k = 0; k < 8; k++) {
        int tc = n0 + cg * 32 + ch * 8 + k;
        float rv = (k < 4) ? r0[k] : r1[k - 4];
        float pmv = (k < 4) ? p0[k] : p1[k - 4];
        float qk = (k < 4) ? q0[k] : q1[k - 4];
        bool keep = (tc <= srow) && (pmv != 0.f);
        float rsm = __expf(rv - 16.f) * invr;
        float e = keep ? __expf(fmaf(qk, 0.03125f, rsm - 16.f)) : 0.f;
        u16 pb = f2bf(e); o[k] = pb; rsum += bf2f(pb);
      }
      *(u16x8*)(pt + ch * 8) = o;
    }
    rsum += __shfl_xor(rsum, 1);
    rsum += __shfl_xor(rsum, 2);
    if ((t & 3) == 0) atomicAdd(&rowsum[b * S_ + srow], rsum);
  }
}

// ------- PV: out = (P @ V) / rowsum; paired tiles (15-mtp, mtp) for balance -------
__global__ __launch_bounds__(256, 2) void attn_pv(
    const u16* __restrict__ P, const u16* __restrict__ vT,
    const float* __restrict__ rowsum, float* __restrict__ out) {
  __shared__ __align__(16) u16 lds[32768];
  int f = xcd_swz(blockIdx.x + 8 * blockIdx.y + 64 * blockIdx.z, 512);
  int mtp = f & 7, dt = (f >> 3) & 7, b = f >> 6;
  for (int hf = 0; hf < 2; hf++) {
    int mt = hf ? mtp : (15 - mtp);        // heavy tile first; cost sum = 17 const
    int m0 = mt * 128, n0 = dt * 128;
    int nT = 2 * (mt + 1);
    f32x4 acc[4][4];
    gemm128<1>(P + (size_t)(b * TRI_ + mt * (mt + 1) / 2) * TELEM_, 128,
               vT + ((size_t)b * D_ + n0) * S_, S_, nT, lds, acc);
    int t = threadIdx.x, w = t >> 6, l = t & 63;
    int wr = w >> 1, wc = w & 1;
    float* fs = (float*)lds;
    #pragma unroll
    for (int h = 0; h < 2; h++) {
      __syncthreads();
      if (wr == h) {
        #pragma unroll
        for (int m = 0; m < 4; m++)
          #pragma unroll
          for (int j = 0; j < 4; j++) {
            int row = m * 16 + (l >> 4) * 4 + j;
            float inv = 1.f / rowsum[b * S_ + m0 + h * 64 + row];
            #pragma unroll
            for (int n = 0; n < 4; n++)
              fs[row * 132 + wc * 64 + n * 16 + (l & 15)] = acc[m][n][j] * inv;
          }
      }
      __syncthreads();
      #pragma unroll
      for (int i = 0; i < 8; i++) {
        int idx = i * 256 + t;
        int row = idx >> 5, c4 = (idx & 31) << 2;
        *(float4*)(out + ((size_t)b * S_ + m0 + h * 64 + row) * D_ + n0 + c4) =
            *(const float4*)(fs + row * 132 + c4);
      }
    }
    __syncthreads();   // protect LDS from next tile's prologue DMA
  }
}

// ---------------- launch ----------------
extern "C" void kernel_launch(void* const* d_in, const int* in_sizes, int n_in,
                              void* d_out, int out_size, void* d_ws, size_t ws_size,
                              hipStream_t stream) {
  const float* x     = (const float*)d_in[0];
  const float* r_mat = (const float*)d_in[1];
  const float* pm    = (const float*)d_in[3];
  const float* Wq    = (const float*)d_in[4];
  const float* Wk    = (const float*)d_in[5];
  const float* Wv    = (const float*)d_in[6];
  float* out = (float*)d_out;
  char* ws = (char*)d_ws;

  const size_t PK = (size_t)B_ * TRI_ * TELEM_ * 2;   // 37,355,520 bytes
  u16*   qb     = (u16*)(ws + 0);
  u16*   kb     = (u16*)(ws + 33554432ULL);
  u16*   vT     = (u16*)(ws + 67108864ULL);
  float* rowsum = (float*)(ws + 100663296ULL);
  float* rs_r   = (float*)(ws + 100728832ULL);
  u16*   xb     = (u16*)(ws + 100794368ULL);            // dead after gemm_qkv
  u16*   Wt     = (u16*)(ws + 134348800ULL);            // dead after gemm_qkv
  u16*   er     = (u16*)(ws + 100794368ULL);            // reuses xb region
  bool use_er   = ws_size >= 100794368ULL + 2 * PK;     // 175,505,408
  u16*   P      = use_er ? (u16*)(ws + 100794368ULL + PK)
                         : (u16*)(ws + 100794368ULL);

  prep<<<dim3(5120), dim3(256), 0, stream>>>(x, Wq, Wk, Wv, xb, Wt);
  if (!use_er)
    r_rowsum<<<dim3(B_ * S_), dim3(256), 0, stream>>>(r_mat, pm, rs_r);
  gemm_qkv<<<dim3(64, 4, 3), dim3(512), 0, stream>>>(xb, Wt, qb, kb, vT);
  if (use_er) {
    er_pass<<<dim3(B_ * S_), dim3(256), 0, stream>>>(r_mat, pm, er, rowsum);
    attn_scores_er<<<dim3(36, 8), dim3(512), 0, stream>>>(qb, kb, er, P, rowsum);
  } else {
    hipMemsetAsync(rowsum, 0, B_ * S_ * sizeof(float), stream);
    attn_scores_rm<<<dim3(136, 8), dim3(256), 0, stream>>>(qb, kb, r_mat, pm, rs_r, P, rowsum);
  }
  attn_pv<<<dim3(8, 8, 8), dim3(256), 0, stream>>>(P, vT, rowsum, out);
}